// Round 1
// baseline (204.827 us; speedup 1.0000x reference)
//
#include <hip/hip_runtime.h>
#include <stdint.h>

#define E_N 8192
#define KVSPLIT 4
#define KVSTEPS ((E_N / KVSPLIT) / 64)   // 32

typedef unsigned short u16;
typedef __attribute__((ext_vector_type(4))) float f32x4;
typedef __attribute__((ext_vector_type(8))) short bf16x8;
typedef __attribute__((ext_vector_type(4))) unsigned int u32x4;
typedef __attribute__((ext_vector_type(2))) unsigned int u32x2;

union V16 { u32x4 q; bf16x8 h; u16 u[8]; };

static __device__ __forceinline__ u16 f2bf(float f) {
  union { float f; unsigned u; } c; c.f = f;
  unsigned r = c.u + 0x7FFFu + ((c.u >> 16) & 1u);
  return (u16)(r >> 16);
}

// q pre-scale folds softmax 1/sqrt(128) and log2(e) so inner loop is exp2.
constexpr float QS = 1.4426950408889634f / 11.313708498984761f;

// ---------- kernel 0: W[256][128] f32 -> Wt bf16 [2][128][256]
__global__ void k_wt(const float* __restrict__ Wq, const float* __restrict__ Wk,
                     u16* __restrict__ wt) {
  int idx = blockIdx.x * 256 + threadIdx.x;          // 0..65535
  int mat = idx >> 15, rem = idx & 32767;
  int d = rem >> 7, c = rem & 127;
  float v = mat ? Wk[rem] : Wq[rem];
  wt[(mat * 128 + c) * 256 + d] = f2bf(v);
}

// ---------- kernel 1: projections q (scaled) and k, bf16 [8192][128]
__launch_bounds__(256)
__global__ void k_proj(const float* __restrict__ X, const u16* __restrict__ wt,
                       u16* __restrict__ qg, u16* __restrict__ kg) {
  __shared__ __align__(16) char Xs[64 * 512];        // bf16 [64][256], xor-swizzled
  const int tid = threadIdx.x;
  const int wid = tid >> 6, lane = tid & 63, g = lane >> 4, l15 = lane & 15;
  const int r0 = blockIdx.x * 64;
#pragma unroll
  for (int i = 0; i < 16; ++i) {
    int s = tid + 256 * i;                           // 0..4095 float4 tasks
    int row = s >> 6, c4 = (s & 63) << 2;
    f32x4 v = *(const f32x4*)(X + (size_t)(r0 + row) * 256 + c4);
    u32x2 pk;
    pk[0] = f2bf(v[0]) | ((unsigned)f2bf(v[1]) << 16);
    pk[1] = f2bf(v[2]) | ((unsigned)f2bf(v[3]) << 16);
    *(u32x2*)(Xs + (((row << 9) + (c4 << 1)) ^ ((row & 7) << 4))) = pk;
  }
  __syncthreads();
  bf16x8 xa[8];
  const int arow = wid * 16 + l15;
#pragma unroll
  for (int ks = 0; ks < 8; ++ks) {
    V16 t; t.q = *(const u32x4*)(Xs + (((arow << 9) + (ks << 6) + (g << 4)) ^ ((l15 & 7) << 4)));
    xa[ks] = t.h;
  }
  const f32x4 zero4 = {0.f, 0.f, 0.f, 0.f};
  f32x4 acc[16];
#pragma unroll
  for (int i = 0; i < 16; ++i) acc[i] = zero4;
#pragma unroll
  for (int ct = 0; ct < 16; ++ct) {
    int mat = ct >> 3, c = ((ct & 7) << 4) + l15;
#pragma unroll
    for (int ks = 0; ks < 8; ++ks) {
      V16 b; b.q = *(const u32x4*)(wt + ((mat * 128 + c) * 256 + (ks << 5) + (g << 3)));
      acc[ct] = __builtin_amdgcn_mfma_f32_16x16x32_bf16(xa[ks], b.h, acc[ct], 0, 0, 0);
    }
  }
#pragma unroll
  for (int ct = 0; ct < 16; ++ct) {
    int mat = ct >> 3, c = ((ct & 7) << 4) + l15;
#pragma unroll
    for (int r = 0; r < 4; ++r) {
      int row = r0 + wid * 16 + 4 * g + r;
      float v = acc[ct][r];
      if (mat == 0) qg[row * 128 + c] = f2bf(v * QS);
      else          kg[row * 128 + c] = f2bf(v);
    }
  }
}

// ---------- kernel 2: kt[128][8192] = k^T (bf16), LDS-tiled transpose
__global__ void k_kt(const u16* __restrict__ kg, u16* __restrict__ ktg) {
  __shared__ __align__(16) u16 Ts[64 * 66];          // pitch 66 (132 B) for bank spread
  const int tid = threadIdx.x;
  const int b = blockIdx.x;
  const int r0 = (b >> 1) * 64, c0 = (b & 1) * 64;
#pragma unroll
  for (int i = 0; i < 2; ++i) {
    int s = tid + 256 * i;                           // 0..511
    int row = s >> 3, seg = s & 7;
    u32x4 v = *(const u32x4*)(kg + (size_t)(r0 + row) * 128 + c0 + seg * 8);
    unsigned* dst = (unsigned*)((char*)Ts + row * 132 + seg * 16);
    dst[0] = v[0]; dst[1] = v[1]; dst[2] = v[2]; dst[3] = v[3];
  }
  __syncthreads();
#pragma unroll
  for (int i = 0; i < 2; ++i) {
    int s = tid + 256 * i;
    int oc = s >> 3, seg2 = s & 7;
    u16 t[8];
#pragma unroll
    for (int j = 0; j < 8; ++j) t[j] = Ts[(seg2 * 8 + j) * 66 + oc];
    u32x4 o;
    o[0] = t[0] | ((unsigned)t[1] << 16);
    o[1] = t[2] | ((unsigned)t[3] << 16);
    o[2] = t[4] | ((unsigned)t[5] << 16);
    o[3] = t[6] | ((unsigned)t[7] << 16);
    *(u32x4*)(ktg + (size_t)(c0 + oc) * E_N + r0 + seg2 * 8) = o;
  }
}

// ---------- kernel 3: fused masked-softmax attention (flash, no-max variant)
__launch_bounds__(256, 2)
__global__ void k_flash(const u16* __restrict__ qg, const u16* __restrict__ kg,
                        const u16* __restrict__ ktg, const int* __restrict__ maskp,
                        float* __restrict__ Op, float* __restrict__ lp) {
  __shared__ __align__(16) char Ksh[64 * 256];       // bf16 [64][128], xor-swizzled
  __shared__ __align__(16) char Kts[128 * 128];      // bf16 [128][64], xor-swizzled
  __shared__ __align__(16) float Psh[4 * 16 * 68];   // per-wave P tile, pitch 68
  const int tid = threadIdx.x;
  const int wid = tid >> 6, lane = tid & 63, g = lane >> 4, l15 = lane & 15;
  const int qb0 = blockIdx.x * 64;
  const int split = blockIdx.y;
  const int kvbase = split * (E_N / KVSPLIT);

  bf16x8 qf[4];
  {
    const u16* qrow = qg + (qb0 + wid * 16 + l15) * 128;
#pragma unroll
    for (int ks = 0; ks < 4; ++ks) {
      V16 t; t.q = *(const u32x4*)(qrow + (ks << 5) + (g << 3));
      qf[ks] = t.h;
    }
  }
  const f32x4 zero4 = {0.f, 0.f, 0.f, 0.f};
  f32x4 Oacc[8];
#pragma unroll
  for (int i = 0; i < 8; ++i) Oacc[i] = zero4;
  float lacc[4] = {0.f, 0.f, 0.f, 0.f};
  float* Pw = Psh + wid * (16 * 68);
  const int* mrow = maskp + (size_t)(qb0 + wid * 16 + 4 * g) * E_N + kvbase + l15;

  for (int st = 0; st < KVSTEPS; ++st) {
    const int kv0 = kvbase + st * 64;
    __syncthreads();
    // stage K tile [64 kv][128 d]
#pragma unroll
    for (int i = 0; i < 4; ++i) {
      int s = tid + 256 * i;                         // 0..1023
      int row = s >> 4, seg = s & 15;
      u32x4 v = *(const u32x4*)(kg + (size_t)(kv0 + row) * 128 + seg * 8);
      *(u32x4*)(Ksh + (((row << 8) + (seg << 4)) ^ ((row & 7) << 4))) = v;
    }
    // stage Kt tile [128 d][64 kv]
#pragma unroll
    for (int i = 0; i < 4; ++i) {
      int s = tid + 256 * i;
      int d = s >> 3, seg = s & 7;
      u32x4 v = *(const u32x4*)(ktg + (size_t)d * E_N + kv0 + seg * 8);
      *(u32x4*)(Kts + (((d << 7) + (seg << 4)) ^ ((d & 7) << 4))) = v;
    }
    __syncthreads();

    // mask tile (the 268 MB HBM stream)
    int m[4][4];
    {
      const int* mb = mrow + st * 64;
#pragma unroll
      for (int t = 0; t < 4; ++t)
#pragma unroll
        for (int r = 0; r < 4; ++r)
          m[t][r] = mb[r * E_N + t * 16];
    }

    // S = q @ k^T (q pre-scaled; result is log2-domain exponent)
    f32x4 S[4];
#pragma unroll
    for (int t = 0; t < 4; ++t) S[t] = zero4;
#pragma unroll
    for (int t = 0; t < 4; ++t) {
      int krow = t * 16 + l15;
#pragma unroll
      for (int ks = 0; ks < 4; ++ks) {
        V16 kf; kf.q = *(const u32x4*)(Ksh + (((krow << 8) + (ks << 6) + (g << 4)) ^ ((l15 & 7) << 4)));
        S[t] = __builtin_amdgcn_mfma_f32_16x16x32_bf16(qf[ks], kf.h, S[t], 0, 0, 0);
      }
    }

    // p = mask ? exp2(S) : 0 ; accumulate l ; bounce P through LDS (D->A layout)
#pragma unroll
    for (int t = 0; t < 4; ++t) {
#pragma unroll
      for (int r = 0; r < 4; ++r) {
        float pv = m[t][r] ? __builtin_amdgcn_exp2f(S[t][r]) : 0.f;
        lacc[r] += pv;
        Pw[(4 * g + r) * 68 + t * 16 + l15] = pv;
      }
    }

    bf16x8 pa[2];
#pragma unroll
    for (int ks2 = 0; ks2 < 2; ++ks2) {
      const float* pp = Pw + l15 * 68 + ks2 * 32 + g * 8;
      f32x4 lo = *(const f32x4*)pp;
      f32x4 hi = *(const f32x4*)(pp + 4);
      V16 t;
      t.u[0] = f2bf(lo[0]); t.u[1] = f2bf(lo[1]); t.u[2] = f2bf(lo[2]); t.u[3] = f2bf(lo[3]);
      t.u[4] = f2bf(hi[0]); t.u[5] = f2bf(hi[1]); t.u[6] = f2bf(hi[2]); t.u[7] = f2bf(hi[3]);
      pa[ks2] = t.h;
    }
    // O += P @ k  (B-frags from transposed Kt tile)
#pragma unroll
    for (int dt = 0; dt < 8; ++dt) {
      int krow = dt * 16 + l15;
#pragma unroll
      for (int ks2 = 0; ks2 < 2; ++ks2) {
        V16 kf; kf.q = *(const u32x4*)(Kts + (((krow << 7) + (ks2 << 6) + (g << 4)) ^ ((l15 & 7) << 4)));
        Oacc[dt] = __builtin_amdgcn_mfma_f32_16x16x32_bf16(pa[ks2], kf.h, Oacc[dt], 0, 0, 0);
      }
    }
  }

  // reduce row sums across the 16 lanes of each group
#pragma unroll
  for (int r = 0; r < 4; ++r) {
    float v = lacc[r];
    v += __shfl_xor(v, 1);
    v += __shfl_xor(v, 2);
    v += __shfl_xor(v, 4);
    v += __shfl_xor(v, 8);
    lacc[r] = v;
  }
  if (l15 == 0) {
#pragma unroll
    for (int r = 0; r < 4; ++r)
      lp[split * E_N + qb0 + wid * 16 + 4 * g + r] = lacc[r];
  }
  float* op = Op + ((size_t)split * E_N + qb0 + wid * 16) * 128;
#pragma unroll
  for (int dt = 0; dt < 8; ++dt)
#pragma unroll
    for (int r = 0; r < 4; ++r)
      op[(4 * g + r) * 128 + dt * 16 + l15] = Oacc[dt][r];
}

// ---------- kernel 4: combine KV-split partials, normalize
__global__ void k_comb(const float* __restrict__ Op, const float* __restrict__ lp,
                       float* __restrict__ out) {
  int idx = blockIdx.x * 256 + threadIdx.x;          // < 8192*128
  int e = idx >> 7;
  float o = 0.f, l = 0.f;
#pragma unroll
  for (int s = 0; s < KVSPLIT; ++s) {
    o += Op[(size_t)s * (E_N * 128) + idx];
    l += lp[s * E_N + e];
  }
  out[idx] = o / l;
}

extern "C" void kernel_launch(void* const* d_in, const int* in_sizes, int n_in,
                              void* d_out, int out_size, void* d_ws, size_t ws_size,
                              hipStream_t stream) {
  const float* X  = (const float*)d_in[0];
  const float* Wq = (const float*)d_in[1];
  const float* Wk = (const float*)d_in[2];
  const int*   M  = (const int*)d_in[3];
  char* ws = (char*)d_ws;
  u16*   qg  = (u16*)(ws);                                   // 2 MB
  u16*   kg  = (u16*)(ws + (size_t)(2u << 20));              // 2 MB
  u16*   ktg = (u16*)(ws + (size_t)(4u << 20));              // 2 MB
  u16*   wt  = (u16*)(ws + (size_t)(6u << 20));              // 128 KB
  float* lp  = (float*)(ws + (size_t)(6u << 20) + (1u << 17));  // 128 KB
  float* Op  = (float*)(ws + (size_t)(6u << 20) + (2u << 17));  // 16 MB
  float* out = (float*)d_out;

  k_wt  <<<256, 256, 0, stream>>>(Wq, Wk, wt);
  k_proj<<<128, 256, 0, stream>>>(X, wt, qg, kg);
  k_kt  <<<256, 256, 0, stream>>>(kg, ktg);
  k_flash<<<dim3(E_N / 64, KVSPLIT), 256, 0, stream>>>(qg, kg, ktg, M, Op, lp);
  k_comb<<<(E_N * 128) / 256, 256, 0, stream>>>(Op, lp, out);
}